// Round 1
// baseline (482.680 us; speedup 1.0000x reference)
//
#include <hip/hip_runtime.h>

// GeneralizedSurfaceLoss on MI355X.
// Key reduction: the reference's iterative 3x3 dilation chamfer == Chebyshev
// distance transform; with BAND_WIDTH=3 only distances 1..3 matter, so the
// whole thing collapses to a 7x7 neighborhood test per pixel.

#define HH 512
#define WW 512
#define BB 8
#define NCLS 4          // target classes 0..3; foreground classes 1..3
#define TILE 16
#define HALO 3
#define LTS (TILE + 2*HALO)   // 22

// ws layout (floats): [0..23] num, [24..47] den, [48..71] mask-count
// index n = b*3 + (c-1)

__global__ __launch_bounds__(256) void gsl_stage1(
    const float* __restrict__ probs,   // [B,4,H,W]
    const int*   __restrict__ target,  // [B,H,W]
    float* __restrict__ ws)
{
    __shared__ uint32_t tile[LTS * LTS];
    __shared__ float red[4][9];

    const int b   = blockIdx.z;
    const int gx0 = blockIdx.x * TILE - HALO;
    const int gy0 = blockIdx.y * TILE - HALO;
    const int tid = threadIdx.y * TILE + threadIdx.x;
    const int* __restrict__ tgt_b = target + b * (HH * WW);

    // Stage target tile + halo into LDS as class bitmask (1<<t); OOB = 0.
    for (int i = tid; i < LTS * LTS; i += 256) {
        int ly = i / LTS, lx = i - ly * LTS;
        int gy = gy0 + ly, gx = gx0 + lx;
        uint32_t bits = 0u;
        if (gy >= 0 && gy < HH && gx >= 0 && gx < WW)
            bits = 1u << (uint32_t)tgt_b[gy * WW + gx];
        tile[i] = bits;
    }
    __syncthreads();

    const int lx = threadIdx.x + HALO;
    const int ly = threadIdx.y + HALO;
    const int gx = blockIdx.x * TILE + threadIdx.x;
    const int gy = blockIdx.y * TILE + threadIdx.y;

    // Ring-cumulative class presence masks: p1 = 3x3 ball, p2 = 5x5, p3 = 7x7.
    uint32_t p1 = 0u, p2 = 0u, p3 = 0u;
    #pragma unroll
    for (int dy = -3; dy <= 3; ++dy) {
        #pragma unroll
        for (int dx = -3; dx <= 3; ++dx) {
            uint32_t v = tile[(ly + dy) * LTS + (lx + dx)];
            const int ady = dy < 0 ? -dy : dy;
            const int adx = dx < 0 ? -dx : dx;
            const int r = ady > adx ? ady : adx;   // compile-time constant
            if (r <= 1) p1 |= v;
            if (r <= 2) p2 |= v;
            p3 |= v;
        }
    }
    const uint32_t cbits = tile[ly * LTS + lx];

    float acc[9];   // num[3], den[3], mc[3]
    #pragma unroll
    for (int k = 0; k < 3; ++k) {
        const int c = k + 1;
        const uint32_t cm = 1u << c;
        const bool v = (cbits & cm) != 0u;
        // presence of opposite-membership pixel within ball r
        const bool a1 = v ? ((p1 & ~cm) != 0u) : ((p1 & cm) != 0u);
        const bool a2 = v ? ((p2 & ~cm) != 0u) : ((p2 & cm) != 0u);
        const bool a3 = v ? ((p3 & ~cm) != 0u) : ((p3 & cm) != 0u);
        const int d = a1 ? 1 : (a2 ? 2 : (a3 ? 3 : 0));
        const float p = probs[(((b * NCLS) + c) * HH + gy) * WW + gx];
        const float err = fabsf(p - (v ? 1.0f : 0.0f));
        acc[k]     = a3 ? err * (float)d : 0.0f;   // num
        acc[3 + k] = a3 ? 1.0f : 0.0f;             // den
        acc[6 + k] = v ? 1.0f : 0.0f;              // mask count
    }

    // wave64 tree reduce, then cross-wave via LDS, then 9 global atomics/block
    const int lane = tid & 63, wave = tid >> 6;
    #pragma unroll
    for (int k = 0; k < 9; ++k) {
        float s = acc[k];
        #pragma unroll
        for (int off = 32; off; off >>= 1)
            s += __shfl_down(s, off, 64);
        acc[k] = s;
    }
    if (lane == 0) {
        #pragma unroll
        for (int k = 0; k < 9; ++k) red[wave][k] = acc[k];
    }
    __syncthreads();
    if (tid == 0) {
        #pragma unroll
        for (int k = 0; k < 9; ++k) {
            float s = red[0][k] + red[1][k] + red[2][k] + red[3][k];
            int kk = k % 3;          // class-1 index within group
            int grp = k / 3;         // 0=num,1=den,2=mc
            atomicAdd(&ws[grp * 24 + b * 3 + kk], s);
        }
    }
}

__global__ __launch_bounds__(64) void gsl_stage2(
    const float* __restrict__ ws, float* __restrict__ out)
{
    const int n = threadIdx.x;
    float loss = 0.0f, incl = 0.0f;
    if (n < 24) {
        const float num = ws[n];
        const float den = ws[24 + n];
        const float mc  = ws[48 + n];
        const bool trivial = (mc == 0.0f) || (mc == (float)(HH * WW));
        if (trivial) {
            // d==0 everywhere, band everywhere -> denom = H*W >= 32
            incl = 1.0f; loss = 0.0f;
        } else if (den >= 32.0f) {
            incl = 1.0f;
            loss = num / (den + 1e-6f);
        }
    }
    #pragma unroll
    for (int off = 32; off; off >>= 1) {
        loss += __shfl_down(loss, off, 64);
        incl += __shfl_down(incl, off, 64);
    }
    if (n == 0) out[0] = loss / (incl + 1e-6f);
}

extern "C" void kernel_launch(void* const* d_in, const int* in_sizes, int n_in,
                              void* d_out, int out_size, void* d_ws, size_t ws_size,
                              hipStream_t stream)
{
    const float* probs  = (const float*)d_in[0];
    const int*   target = (const int*)d_in[1];
    float* out = (float*)d_out;
    float* ws  = (float*)d_ws;

    hipMemsetAsync(ws, 0, 72 * sizeof(float), stream);

    dim3 grid(WW / TILE, HH / TILE, BB);
    dim3 block(TILE, TILE);
    gsl_stage1<<<grid, block, 0, stream>>>(probs, target, ws);
    gsl_stage2<<<1, 64, 0, stream>>>(ws, out);
}

// Round 2
// 94.569 us; speedup vs baseline: 5.1040x; 5.1040x over previous
//
#include <hip/hip_runtime.h>

// GeneralizedSurfaceLoss on MI355X.
// Chamfer == Chebyshev distance; BAND_WIDTH=3 => only a 7x7 neighborhood test.
// R1: replaced 73k same-cacheline global atomics (the 435us serialization)
// with per-block private stores + deterministic 2-level tree reduction.
// 32x32 tile / 4 px per thread; LDS stride 40 => pure 2-way bank aliasing (free).

#define HH 512
#define WW 512
#define BB 8
#define NCLS 4
#define TILE 32
#define HALO 3
#define LTS (TILE + 2*HALO)   // 38
#define LSTRIDE 40            // bank-friendly row stride
#define NBLK 2048             // 16*16*8 stage-1 blocks
#define WS2_OFF (9 * NBLK)    // float offset of second-level sums

// ws: [0 .. 9*2048)   per-block partials, slot = (grp*3+cc)*2048 + blockFlat
//     [WS2_OFF .. +72) reduced sums: grp*24 + b*3 + cc  (grp: 0=num,1=den,2=mc)

__global__ __launch_bounds__(256) void gsl_stage1(
    const float* __restrict__ probs,   // [B,4,H,W]
    const int*   __restrict__ target,  // [B,H,W]
    float* __restrict__ ws)
{
    __shared__ uint32_t tile[LTS * LSTRIDE];
    __shared__ float redf[4][3];
    __shared__ int   redi[4][3];

    const int b   = blockIdx.z;
    const int gx0 = blockIdx.x * TILE - HALO;
    const int gy0 = blockIdx.y * TILE - HALO;
    const int tid = threadIdx.y * 16 + threadIdx.x;
    const int* __restrict__ tgt_b = target + b * (HH * WW);

    // Stage target tile + halo as class bitmask (1<<t); OOB = 0.
    for (int i = tid; i < LTS * LTS; i += 256) {
        int ly = i / LTS, lx = i - ly * LTS;
        int gy = gy0 + ly, gx = gx0 + lx;
        uint32_t bits = 0u;
        if ((unsigned)gy < (unsigned)HH && (unsigned)gx < (unsigned)WW)
            bits = 1u << (uint32_t)tgt_b[gy * WW + gx];
        tile[ly * LSTRIDE + lx] = bits;
    }
    __syncthreads();

    float num[3] = {0.f, 0.f, 0.f};
    int   den[3] = {0, 0, 0};
    int   mc [3] = {0, 0, 0};

    #pragma unroll
    for (int sy = 0; sy < 2; ++sy)
    #pragma unroll
    for (int sx = 0; sx < 2; ++sx) {
        const int px = threadIdx.x + 16 * sx;     // 0..31 within tile
        const int py = threadIdx.y + 16 * sy;
        const int lx = px + HALO, ly = py + HALO;
        const int gx = blockIdx.x * TILE + px;
        const int gy = blockIdx.y * TILE + py;

        // Ring-cumulative class presence: p1 = 3x3 ball, p2 = 5x5, p3 = 7x7.
        uint32_t p1 = 0u, p2 = 0u, p3 = 0u;
        #pragma unroll
        for (int dy = -3; dy <= 3; ++dy) {
            #pragma unroll
            for (int dx = -3; dx <= 3; ++dx) {
                uint32_t v = tile[(ly + dy) * LSTRIDE + (lx + dx)];
                const int ady = dy < 0 ? -dy : dy;
                const int adx = dx < 0 ? -dx : dx;
                const int r = ady > adx ? ady : adx;  // compile-time const
                if (r <= 1) p1 |= v;
                if (r <= 2) p2 |= v;
                p3 |= v;
            }
        }
        const uint32_t cbits = tile[ly * LSTRIDE + lx];

        #pragma unroll
        for (int k = 0; k < 3; ++k) {
            const int c = k + 1;
            const uint32_t cm = 1u << c;
            const bool v = (cbits & cm) != 0u;
            const bool a1 = v ? ((p1 & ~cm) != 0u) : ((p1 & cm) != 0u);
            const bool a2 = v ? ((p2 & ~cm) != 0u) : ((p2 & cm) != 0u);
            const bool a3 = v ? ((p3 & ~cm) != 0u) : ((p3 & cm) != 0u);
            const int d = a1 ? 1 : (a2 ? 2 : 3);
            const float p = probs[(((b * NCLS) + c) * HH + gy) * WW + gx];
            const float err = fabsf(p - (v ? 1.0f : 0.0f));
            num[k] += a3 ? err * (float)d : 0.0f;
            den[k] += a3 ? 1 : 0;
            mc [k] += v ? 1 : 0;
        }
    }

    // Pack 6 small counters into 3 ints (16-bit fields; block sums <= 1024).
    int pk0 = den[0] | (den[1] << 16);
    int pk1 = den[2] | (mc[0] << 16);
    int pk2 = mc[1]  | (mc[2] << 16);

    const int lane = tid & 63, wave = tid >> 6;
    #pragma unroll
    for (int off = 32; off; off >>= 1) {
        num[0] += __shfl_down(num[0], off, 64);
        num[1] += __shfl_down(num[1], off, 64);
        num[2] += __shfl_down(num[2], off, 64);
        pk0    += __shfl_down(pk0,    off, 64);
        pk1    += __shfl_down(pk1,    off, 64);
        pk2    += __shfl_down(pk2,    off, 64);
    }
    if (lane == 0) {
        redf[wave][0] = num[0]; redf[wave][1] = num[1]; redf[wave][2] = num[2];
        redi[wave][0] = pk0;    redi[wave][1] = pk1;    redi[wave][2] = pk2;
    }
    __syncthreads();
    if (tid == 0) {
        const int blockFlat = ((b * 16) + blockIdx.y) * 16 + blockIdx.x;
        float n0 = 0.f, n1 = 0.f, n2 = 0.f;
        int s0 = 0, s1 = 0, s2 = 0;
        #pragma unroll
        for (int w = 0; w < 4; ++w) {
            n0 += redf[w][0]; n1 += redf[w][1]; n2 += redf[w][2];
            s0 += redi[w][0]; s1 += redi[w][1]; s2 += redi[w][2];
        }
        // grp 0 = num
        ws[(0 * 3 + 0) * NBLK + blockFlat] = n0;
        ws[(0 * 3 + 1) * NBLK + blockFlat] = n1;
        ws[(0 * 3 + 2) * NBLK + blockFlat] = n2;
        // grp 1 = den
        ws[(1 * 3 + 0) * NBLK + blockFlat] = (float)(s0 & 0xFFFF);
        ws[(1 * 3 + 1) * NBLK + blockFlat] = (float)(s0 >> 16);
        ws[(1 * 3 + 2) * NBLK + blockFlat] = (float)(s1 & 0xFFFF);
        // grp 2 = mask count
        ws[(2 * 3 + 0) * NBLK + blockFlat] = (float)(s1 >> 16);
        ws[(2 * 3 + 1) * NBLK + blockFlat] = (float)(s2 & 0xFFFF);
        ws[(2 * 3 + 2) * NBLK + blockFlat] = (float)(s2 >> 16);
    }
}

// 72 blocks: g = blockIdx.x; k = g/8 (grp*3+cc), b = g%8.
// Each reduces the 256 partials of (k, b).
__global__ __launch_bounds__(256) void gsl_stage2(float* __restrict__ ws)
{
    __shared__ float red[4];
    const int g = blockIdx.x;
    const int k = g >> 3, b = g & 7;
    const int tid = threadIdx.x;

    float s = ws[k * NBLK + b * 256 + tid];
    #pragma unroll
    for (int off = 32; off; off >>= 1) s += __shfl_down(s, off, 64);
    if ((tid & 63) == 0) red[tid >> 6] = s;
    __syncthreads();
    if (tid == 0) {
        const int grp = k / 3, cc = k % 3;
        ws[WS2_OFF + grp * 24 + b * 3 + cc] = red[0] + red[1] + red[2] + red[3];
    }
}

__global__ __launch_bounds__(64) void gsl_stage3(
    const float* __restrict__ ws, float* __restrict__ out)
{
    const float* ws2 = ws + WS2_OFF;
    const int n = threadIdx.x;
    float loss = 0.0f, incl = 0.0f;
    if (n < 24) {
        const float num = ws2[n];
        const float den = ws2[24 + n];
        const float mcv = ws2[48 + n];
        const bool trivial = (mcv == 0.0f) || (mcv == (float)(HH * WW));
        if (trivial) {
            incl = 1.0f; loss = 0.0f;   // band = whole image, num = 0
        } else if (den >= 32.0f) {
            incl = 1.0f;
            loss = num / (den + 1e-6f);
        }
    }
    #pragma unroll
    for (int off = 32; off; off >>= 1) {
        loss += __shfl_down(loss, off, 64);
        incl += __shfl_down(incl, off, 64);
    }
    if (n == 0) out[0] = loss / (incl + 1e-6f);
}

extern "C" void kernel_launch(void* const* d_in, const int* in_sizes, int n_in,
                              void* d_out, int out_size, void* d_ws, size_t ws_size,
                              hipStream_t stream)
{
    const float* probs  = (const float*)d_in[0];
    const int*   target = (const int*)d_in[1];
    float* out = (float*)d_out;
    float* ws  = (float*)d_ws;

    dim3 grid1(WW / TILE, HH / TILE, BB);   // 16 x 16 x 8
    dim3 block1(16, 16);
    gsl_stage1<<<grid1, block1, 0, stream>>>(probs, target, ws);
    gsl_stage2<<<72, 256, 0, stream>>>(ws);
    gsl_stage3<<<1, 64, 0, stream>>>(ws, out);
}

// Round 3
// 84.508 us; speedup vs baseline: 5.7117x; 1.1191x over previous
//
#include <hip/hip_runtime.h>

// GeneralizedSurfaceLoss on MI355X.
// Chamfer == Chebyshev distance; BAND_WIDTH=3 => 7x7 neighborhood test.
// R1: killed global-atomic serialization (483 -> 95 us).
// R2: nibble-packed separable window. 8 px / uint32 (4-bit class masks);
//     horizontal 3/5/7-wide OR via funnel shifts + __shfl neighbors (no LDS);
//     vertical OR via 7 ds_read_b128 per 8 px. Row-strip blocks, all global
//     traffic int4/float4. Stage2+3 fused into one block. HBM floor ~5.9 us.

#define HH 512
#define WW 512
#define BB 8
#define STRIP 8               // output rows per block
#define SROWS (STRIP + 6)     // staged rows incl. halo = 14
#define NBLK 512              // 64 strips * 8 images

// ws: 9 arrays of NBLK floats; slot s = grp*3+cc (grp: 0=num,1=den,2=mc),
// element index blockFlat = b*64 + strip.

__global__ __launch_bounds__(256) void gsl_stage1(
    const float* __restrict__ probs,   // [B,4,H,W]
    const int*   __restrict__ target,  // [B,H,W]
    float* __restrict__ ws)
{
    __shared__ uint4 hrow[SROWS * 64];   // {h1,h2,h3,center} per (row,lane)
    __shared__ float redf[4][3];
    __shared__ int   redi[4][3];

    const int tid   = threadIdx.x;
    const int lane  = tid & 63;
    const int wave  = tid >> 6;
    const int strip = blockIdx.x;        // 0..63
    const int b     = blockIdx.y;        // 0..7
    const int y0    = strip * STRIP;
    const int* __restrict__ tgt_b = target + b * (HH * WW);

    // ---- phase 1: pack rows y0-3 .. y0+STRIP+2 (wave-cyclic row assignment)
    #pragma unroll
    for (int i = 0; i < 4; ++i) {
        const int ri = wave + 4 * i;
        if (ri < SROWS) {
            const int gy = y0 - 3 + ri;
            uint32_t wv = 0u, h1 = 0u, h2 = 0u, h3 = 0u;
            if ((unsigned)gy < (unsigned)HH) {
                const int4* trow = (const int4*)(tgt_b + gy * WW);
                const int4 t0 = trow[lane * 2];
                const int4 t1 = trow[lane * 2 + 1];
                wv = (1u << t0.x)        | (1u << (t0.y + 4))
                   | (1u << (t0.z + 8))  | (1u << (t0.w + 12))
                   | (1u << (t1.x + 16)) | (1u << (t1.y + 20))
                   | (1u << (t1.z + 24)) | (1u << (t1.w + 28));
                uint32_t wl = __shfl_up(wv, 1, 64);   if (lane == 0)  wl = 0u;
                uint32_t wr = __shfl_down(wv, 1, 64); if (lane == 63) wr = 0u;
                h1 = wv | ((wv << 4)  | (wl >> 28)) | ((wv >> 4)  | (wr << 28));
                h2 = h1 | ((wv << 8)  | (wl >> 24)) | ((wv >> 8)  | (wr << 24));
                h3 = h2 | ((wv << 12) | (wl >> 20)) | ((wv >> 12) | (wr << 20));
            }
            hrow[ri * 64 + lane] = make_uint4(h1, h2, h3, wv);
        }
    }
    __syncthreads();

    // ---- phase 2: each wave computes 2 output rows
    float num[3] = {0.f, 0.f, 0.f};
    int   den[3] = {0, 0, 0};
    int   mc [3] = {0, 0, 0};

    #pragma unroll
    for (int t = 0; t < 2; ++t) {
        const int yo = wave * 2 + t;
        const int gy = y0 + yo;
        const int lr = yo + 3;

        const float4* pr1 = (const float4*)(probs + (size_t)(((b * 4) + 1) * HH + gy) * WW);
        const float4* pr2 = (const float4*)(probs + (size_t)(((b * 4) + 2) * HH + gy) * WW);
        const float4* pr3 = (const float4*)(probs + (size_t)(((b * 4) + 3) * HH + gy) * WW);
        const float4 f1a = pr1[lane * 2], f1b = pr1[lane * 2 + 1];
        const float4 f2a = pr2[lane * 2], f2b = pr2[lane * 2 + 1];
        const float4 f3a = pr3[lane * 2], f3b = pr3[lane * 2 + 1];

        const uint4 r0 = hrow[(lr - 3) * 64 + lane];
        const uint4 r1 = hrow[(lr - 2) * 64 + lane];
        const uint4 r2 = hrow[(lr - 1) * 64 + lane];
        const uint4 r3 = hrow[(lr    ) * 64 + lane];
        const uint4 r4 = hrow[(lr + 1) * 64 + lane];
        const uint4 r5 = hrow[(lr + 2) * 64 + lane];
        const uint4 r6 = hrow[(lr + 3) * 64 + lane];
        const uint32_t p1 = r2.x | r3.x | r4.x;
        const uint32_t p2 = r1.y | r2.y | r3.y | r4.y | r5.y;
        const uint32_t p3 = r0.z | r1.z | r2.z | r3.z | r4.z | r5.z | r6.z;
        const uint32_t cw = r3.w;

        const float pv[3][8] = {
            {f1a.x, f1a.y, f1a.z, f1a.w, f1b.x, f1b.y, f1b.z, f1b.w},
            {f2a.x, f2a.y, f2a.z, f2a.w, f2b.x, f2b.y, f2b.z, f2b.w},
            {f3a.x, f3a.y, f3a.z, f3a.w, f3b.x, f3b.y, f3b.z, f3b.w}};

        #pragma unroll
        for (int j = 0; j < 8; ++j) {
            const uint32_t q1 = (p1 >> (4 * j)) & 15u;
            const uint32_t q2 = (p2 >> (4 * j)) & 15u;
            const uint32_t q3 = (p3 >> (4 * j)) & 15u;
            const uint32_t cb = (cw >> (4 * j)) & 15u;
            #pragma unroll
            for (int k = 0; k < 3; ++k) {
                const uint32_t cm = 2u << k;          // 1<<(k+1)
                const bool v = (cb & cm) != 0u;
                const uint32_t sel = v ? (15u & ~cm) : cm;
                const uint32_t a1 = q1 & sel;
                const uint32_t a2 = q2 & sel;
                const uint32_t a3 = q3 & sel;
                const float df  = a1 ? 1.f : (a2 ? 2.f : 3.f);
                const float err = fabsf(pv[k][j] - (v ? 1.f : 0.f));
                num[k] += a3 ? err * df : 0.f;
                den[k] += a3 ? 1 : 0;
                mc [k] += v  ? 1 : 0;
            }
        }
    }

    // ---- block reduction (den/mc <= 1024 after 64-lane sum: 16-bit safe)
    int pk0 = den[0] | (den[1] << 16);
    int pk1 = den[2] | (mc[0] << 16);
    int pk2 = mc[1]  | (mc[2] << 16);
    #pragma unroll
    for (int off = 32; off; off >>= 1) {
        num[0] += __shfl_down(num[0], off, 64);
        num[1] += __shfl_down(num[1], off, 64);
        num[2] += __shfl_down(num[2], off, 64);
        pk0    += __shfl_down(pk0,    off, 64);
        pk1    += __shfl_down(pk1,    off, 64);
        pk2    += __shfl_down(pk2,    off, 64);
    }
    if (lane == 0) {
        redf[wave][0] = num[0]; redf[wave][1] = num[1]; redf[wave][2] = num[2];
        redi[wave][0] = pk0;    redi[wave][1] = pk1;    redi[wave][2] = pk2;
    }
    __syncthreads();
    if (tid == 0) {
        const int blockFlat = b * 64 + strip;
        float n0 = 0.f, n1 = 0.f, n2 = 0.f;
        int s0 = 0, s1 = 0, s2 = 0;
        #pragma unroll
        for (int w = 0; w < 4; ++w) {
            n0 += redf[w][0]; n1 += redf[w][1]; n2 += redf[w][2];
            s0 += redi[w][0]; s1 += redi[w][1]; s2 += redi[w][2];
        }
        ws[(0 * 3 + 0) * NBLK + blockFlat] = n0;
        ws[(0 * 3 + 1) * NBLK + blockFlat] = n1;
        ws[(0 * 3 + 2) * NBLK + blockFlat] = n2;
        ws[(1 * 3 + 0) * NBLK + blockFlat] = (float)(s0 & 0xFFFF);
        ws[(1 * 3 + 1) * NBLK + blockFlat] = (float)(s0 >> 16);
        ws[(1 * 3 + 2) * NBLK + blockFlat] = (float)(s1 & 0xFFFF);
        ws[(2 * 3 + 0) * NBLK + blockFlat] = (float)(s1 >> 16);
        ws[(2 * 3 + 1) * NBLK + blockFlat] = (float)(s2 & 0xFFFF);
        ws[(2 * 3 + 2) * NBLK + blockFlat] = (float)(s2 >> 16);
    }
}

// Single block, 16 waves: 72 group-reductions of 64 strip-partials, then the
// final 24-mask loss in wave 0.
__global__ __launch_bounds__(1024) void gsl_finish(
    const float* __restrict__ ws, float* __restrict__ out)
{
    __shared__ float ws2[72];
    const int tid = threadIdx.x, lane = tid & 63, wave = tid >> 6;

    for (int g = wave; g < 72; g += 16) {
        const int grp = g / 24, rem = g - grp * 24;
        const int bb = rem / 3, cc = rem - bb * 3;
        float s = ws[(grp * 3 + cc) * NBLK + bb * 64 + lane];
        #pragma unroll
        for (int off = 32; off; off >>= 1) s += __shfl_down(s, off, 64);
        if (lane == 0) ws2[g] = s;
    }
    __syncthreads();

    if (wave == 0) {
        float loss = 0.f, incl = 0.f;
        if (lane < 24) {
            const float num = ws2[lane];
            const float den = ws2[24 + lane];
            const float mcv = ws2[48 + lane];
            const bool trivial = (mcv == 0.f) || (mcv == (float)(HH * WW));
            if (trivial) {
                incl = 1.f; loss = 0.f;        // band = whole image, num = 0
            } else if (den >= 32.f) {
                incl = 1.f;
                loss = num / (den + 1e-6f);
            }
        }
        #pragma unroll
        for (int off = 32; off; off >>= 1) {
            loss += __shfl_down(loss, off, 64);
            incl += __shfl_down(incl, off, 64);
        }
        if (lane == 0) out[0] = loss / (incl + 1e-6f);
    }
}

extern "C" void kernel_launch(void* const* d_in, const int* in_sizes, int n_in,
                              void* d_out, int out_size, void* d_ws, size_t ws_size,
                              hipStream_t stream)
{
    const float* probs  = (const float*)d_in[0];
    const int*   target = (const int*)d_in[1];
    float* out = (float*)d_out;
    float* ws  = (float*)d_ws;

    dim3 grid1(64, BB);        // 64 row-strips x 8 images
    gsl_stage1<<<grid1, 256, 0, stream>>>(probs, target, ws);
    gsl_finish<<<1, 1024, 0, stream>>>(ws, out);
}